// Round 15
// baseline (3910.176 us; speedup 1.0000x reference)
//
#include <hip/hip_runtime.h>

#define NB 256      // batch
#define TT 1000     // total timesteps
#define HD 128      // hidden
#define NG 512      // 4*H, PyTorch gate order i,f,g,o
#define SS 8        // slab: timesteps per LDS stage

#define WGA __attribute__((amdgpu_flat_work_group_size(512,512), amdgpu_waves_per_eu(2,2)))

typedef __attribute__((ext_vector_type(8))) short s8v;   // 8 bf16 = 4 VGPR (MFMA A/B)
typedef __attribute__((ext_vector_type(4))) float f4v;   // MFMA C/D

// LDS-only barrier (global stores drain async; r14-verified correct).
#define BAR_LGKM() asm volatile("s_waitcnt lgkmcnt(0)\n\ts_barrier" ::: "memory")

__device__ __forceinline__ unsigned short bf16rne(float v) {
    unsigned u = __float_as_uint(v);
    unsigned r = u + 0x7FFF + ((u >> 16) & 1);
    return (unsigned short)(r >> 16);
}
__device__ __forceinline__ float bf16tof(unsigned short h) {
    return __uint_as_float(((unsigned)h) << 16);
}
__device__ __forceinline__ float sigf(float x) { return 1.f / (1.f + __expf(-x)); }
__device__ __forceinline__ float tanhfast(float x) {
    float e = __expf(-2.f * x);
    return 2.f / (1.f + e) - 1.f;
}

// Load W rows [64*wv, 64*wv+64) as hi/lo bf16 A-fragments (r12-verified map):
// A map (16x16x32): m = lane&15, k = (lane>>4)*4 + (e&3) + 16*(e>>2).
#define LOAD_A(W)                                                              \
    {                                                                          \
        _Pragma("unroll")                                                      \
        for (int t = 0; t < 4; ++t) {                                          \
            const int m = 64*wv + 16*t + lm;                                   \
            const float* wrow = (W) + (size_t)m * HD;                          \
            _Pragma("unroll")                                                  \
            for (int kc = 0; kc < 4; ++kc) {                                   \
                const int k0 = 32*kc + 4*lq;                                   \
                float4 va = *(const float4*)(wrow + k0);                       \
                float4 vb = *(const float4*)(wrow + k0 + 16);                  \
                float vs[8] = {va.x,va.y,va.z,va.w,vb.x,vb.y,vb.z,vb.w};       \
                s8v ah, al;                                                    \
                _Pragma("unroll")                                              \
                for (int e = 0; e < 8; ++e) {                                  \
                    unsigned short hb = bf16rne(vs[e]);                        \
                    float lo = vs[e] - bf16tof(hb);                            \
                    ah[e] = (short)hb; al[e] = (short)bf16rne(lo);             \
                }                                                              \
                Ah[t][kc] = ah; Al[t][kc] = al;                                \
            }                                                                  \
        }                                                                      \
    }

// Build B fragments (h replicated across N-cols) from packed bf16 LDS (r12-verified).
#define BUILD_B(hhi, hlo)                                                      \
    {                                                                          \
        _Pragma("unroll")                                                      \
        for (int kc = 0; kc < 4; ++kc) {                                       \
            const int k0 = 32*kc + 4*lq;                                       \
            union { uint4 u; s8v s; } cv;                                      \
            uint2 pa = *(const uint2*)&(hhi)[k0];                              \
            uint2 pb = *(const uint2*)&(hhi)[k0+16];                           \
            cv.u.x = pa.x; cv.u.y = pa.y; cv.u.z = pb.x; cv.u.w = pb.y;        \
            Bh[kc] = cv.s;                                                     \
            uint2 qa = *(const uint2*)&(hlo)[k0];                              \
            uint2 qb = *(const uint2*)&(hlo)[k0+16];                           \
            cv.u.x = qa.x; cv.u.y = qa.y; cv.u.z = qb.x; cv.u.w = qb.y;        \
            Bl[kc] = cv.s;                                                     \
        }                                                                      \
    }

// Reordered 3-pass hi/lo MFMA: kc-outer, tile-inner -> dependent distance 4
// (x2 waves = 8 independent streams, >= latency/issue) vs r12's distance-3
// chains that stalled ~17cyc/MFMA (MfmaUtil 45% at 1.6us/step).
// accA = Ah*Bh ; accB = Al*Bh + Ah*Bl ; D = accA + accB.
#define MFMA_GATES()                                                           \
    {                                                                          \
        f4v zA = {0.f,0.f,0.f,0.f};                                            \
        f4v A0=zA, A1=zA, A2=zA, A3=zA, B0=zA, B1=zA, B2=zA, B3=zA;            \
        _Pragma("unroll")                                                      \
        for (int kc = 0; kc < 4; ++kc) {                                       \
            A0 = __builtin_amdgcn_mfma_f32_16x16x32_bf16(Ah[0][kc], Bh[kc], A0, 0,0,0); \
            A1 = __builtin_amdgcn_mfma_f32_16x16x32_bf16(Ah[1][kc], Bh[kc], A1, 0,0,0); \
            A2 = __builtin_amdgcn_mfma_f32_16x16x32_bf16(Ah[2][kc], Bh[kc], A2, 0,0,0); \
            A3 = __builtin_amdgcn_mfma_f32_16x16x32_bf16(Ah[3][kc], Bh[kc], A3, 0,0,0); \
        }                                                                      \
        _Pragma("unroll")                                                      \
        for (int kc = 0; kc < 4; ++kc) {                                       \
            B0 = __builtin_amdgcn_mfma_f32_16x16x32_bf16(Al[0][kc], Bh[kc], B0, 0,0,0); \
            B1 = __builtin_amdgcn_mfma_f32_16x16x32_bf16(Al[1][kc], Bh[kc], B1, 0,0,0); \
            B2 = __builtin_amdgcn_mfma_f32_16x16x32_bf16(Al[2][kc], Bh[kc], B2, 0,0,0); \
            B3 = __builtin_amdgcn_mfma_f32_16x16x32_bf16(Al[3][kc], Bh[kc], B3, 0,0,0); \
        }                                                                      \
        _Pragma("unroll")                                                      \
        for (int kc = 0; kc < 4; ++kc) {                                       \
            B0 = __builtin_amdgcn_mfma_f32_16x16x32_bf16(Ah[0][kc], Bl[kc], B0, 0,0,0); \
            B1 = __builtin_amdgcn_mfma_f32_16x16x32_bf16(Ah[1][kc], Bl[kc], B1, 0,0,0); \
            B2 = __builtin_amdgcn_mfma_f32_16x16x32_bf16(Ah[2][kc], Bl[kc], B2, 0,0,0); \
            B3 = __builtin_amdgcn_mfma_f32_16x16x32_bf16(Ah[3][kc], Bl[kc], B3, 0,0,0); \
        }                                                                      \
        if (lm == 0) {                                                         \
            float4 o;                                                          \
            o.x=A0[0]+B0[0]; o.y=A0[1]+B0[1]; o.z=A0[2]+B0[2]; o.w=A0[3]+B0[3];\
            *(float4*)&gbuf[64*wv + 16*0 + 4*lq] = o;                          \
            o.x=A1[0]+B1[0]; o.y=A1[1]+B1[1]; o.z=A1[2]+B1[2]; o.w=A1[3]+B1[3];\
            *(float4*)&gbuf[64*wv + 16*1 + 4*lq] = o;                          \
            o.x=A2[0]+B2[0]; o.y=A2[1]+B2[1]; o.z=A2[2]+B2[2]; o.w=A2[3]+B2[3];\
            *(float4*)&gbuf[64*wv + 16*2 + 4*lq] = o;                          \
            o.x=A3[0]+B3[0]; o.y=A3[1]+B3[1]; o.z=A3[2]+B3[2]; o.w=A3[3]+B3[3];\
            *(float4*)&gbuf[64*wv + 16*3 + 4*lq] = o;                          \
        }                                                                      \
    }

// ---------------- K1: layer-0 recurrence, MFMA hi/lo, distributed update ----------------
// Row r handled by thread 4r (16 active lanes in EVERY wave -> update issue /4).
__global__ WGA
void lstm_layer0(const float* __restrict__ x,
                 const float* __restrict__ Wih, const float* __restrict__ Whh,
                 const float* __restrict__ bih, const float* __restrict__ bhh,
                 float* __restrict__ h1c,
                 float* __restrict__ hstate, float* __restrict__ cstate,
                 int t0, int len)
{
    __shared__ __align__(16) unsigned short hhi[HD], hlo[HD];
    __shared__ float gbuf[NG];
    __shared__ float x_lds[3 * TT];
    const int j = threadIdx.x;
    const int b = blockIdx.x;
    const int wv = j >> 6, lane = j & 63, lq = lane >> 4, lm = lane & 15;
    const bool hnd = ((j & 3) == 0);   // handler thread for row r
    const int r = j >> 2;              // 0..127

    s8v Ah[4][4], Al[4][4];
    LOAD_A(Whh);

    float wx[12], bs[4];
    if (hnd) {
        #pragma unroll
        for (int g = 0; g < 4; ++g) {
            const int row = g*HD + r;
            wx[3*g+0] = Wih[row*3+0]; wx[3*g+1] = Wih[row*3+1]; wx[3*g+2] = Wih[row*3+2];
            bs[g] = bih[row] + bhh[row];
        }
    }

    for (int idx = j; idx < 3*len; idx += 512)
        x_lds[idx] = x[((size_t)b*TT + t0)*3 + idx];

    float c = 0.f, hcur = 0.f;
    if (hnd) {
        if (t0 != 0) { hcur = hstate[b*HD+r]; c = cstate[b*HD+r]; }
        unsigned short hb = bf16rne(hcur);
        hhi[r] = hb; hlo[r] = bf16rne(hcur - bf16tof(hb));
    }
    __syncthreads();

    for (int tc = 0; tc < len; ++tc) {
        s8v Bh[4], Bl[4];
        BUILD_B(hhi, hlo);
        MFMA_GATES();
        BAR_LGKM();                      // barrier A: raw gates visible
        if (hnd) {
            const float x0 = x_lds[3*tc+0], x1 = x_lds[3*tc+1], x2 = x_lds[3*tc+2];
            float gi = gbuf[r]      + bs[0] + wx[0]*x0 + wx[1]*x1 + wx[2]*x2;
            float gf = gbuf[HD+r]   + bs[1] + wx[3]*x0 + wx[4]*x1 + wx[5]*x2;
            float gg = gbuf[2*HD+r] + bs[2] + wx[6]*x0 + wx[7]*x1 + wx[8]*x2;
            float go = gbuf[3*HD+r] + bs[3] + wx[9]*x0 + wx[10]*x1 + wx[11]*x2;
            float iv = sigf(gi), fv = sigf(gf), gv = tanhfast(gg), ov = sigf(go);
            c = fmaf(fv, c, iv*gv);
            hcur = ov * tanhfast(c);
            h1c[((size_t)b*len + tc)*HD + r] = hcur;
            unsigned short hb = bf16rne(hcur);
            hhi[r] = hb; hlo[r] = bf16rne(hcur - bf16tof(hb));
        }
        BAR_LGKM();                      // barrier B: new h visible
    }
    if (hnd) { hstate[b*HD+r] = hcur; cstate[b*HD+r] = c; }
}

// ---------------- K2: xg1 = h1 @ W_ih_l1^T + biases (fp32 VALU, r10-proven) ----------------
#define DOT128(h4, wvv, A0, A1, A2, A3)                                        \
    {                                                                          \
        float4 c0=(h4)[0], c1=(h4)[1], c2=(h4)[2], c3=(h4)[3];                 \
        _Pragma("unroll")                                                      \
        for (int g = 0; g < 8; ++g) {                                          \
            float4 n0,n1,n2,n3;                                                \
            if (g < 7) { n0=(h4)[4*g+4]; n1=(h4)[4*g+5];                       \
                         n2=(h4)[4*g+6]; n3=(h4)[4*g+7]; }                     \
            A0 = fmaf(c0.x, wvv[4*g+0].x, A0); A1 = fmaf(c0.y, wvv[4*g+0].y, A1);\
            A2 = fmaf(c0.z, wvv[4*g+0].z, A2); A3 = fmaf(c0.w, wvv[4*g+0].w, A3);\
            A0 = fmaf(c1.x, wvv[4*g+1].x, A0); A1 = fmaf(c1.y, wvv[4*g+1].y, A1);\
            A2 = fmaf(c1.z, wvv[4*g+1].z, A2); A3 = fmaf(c1.w, wvv[4*g+1].w, A3);\
            A0 = fmaf(c2.x, wvv[4*g+2].x, A0); A1 = fmaf(c2.y, wvv[4*g+2].y, A1);\
            A2 = fmaf(c2.z, wvv[4*g+2].z, A2); A3 = fmaf(c2.w, wvv[4*g+2].w, A3);\
            A0 = fmaf(c3.x, wvv[4*g+3].x, A0); A1 = fmaf(c3.y, wvv[4*g+3].y, A1);\
            A2 = fmaf(c3.z, wvv[4*g+3].z, A2); A3 = fmaf(c3.w, wvv[4*g+3].w, A3);\
            __builtin_amdgcn_sched_barrier(0);                                 \
            if (g < 7) { c0=n0; c1=n1; c2=n2; c3=n3; }                         \
        }                                                                      \
    }

__global__ WGA
void xgate_gemm(const float* __restrict__ h1c,
                const float* __restrict__ Wih1,
                const float* __restrict__ bih1, const float* __restrict__ bhh1,
                float* __restrict__ xg1c, int len)
{
    __shared__ __align__(16) float hrows[SS][HD];
    const int j = threadIdx.x;
    const int b = blockIdx.x;
    float4 wvv[HD/4];
    {
        const float4* wr = (const float4*)(Wih1 + (size_t)j * HD);
        #pragma unroll
        for (int q = 0; q < HD/4; ++q) wvv[q] = wr[q];
    }
    const float bias = bih1[j] + bhh1[j];

    for (int ts = 0; ts < len; ts += SS) {
        const int ns = (len - ts < SS) ? (len - ts) : SS;
        BAR_LGKM();
        for (int idx = j; idx < ns * HD; idx += 512)
            hrows[idx >> 7][idx & 127] = h1c[((size_t)b*len + ts)*HD + idx];
        BAR_LGKM();
        for (int s = 0; s < ns; ++s) {
            float a0=0.f,a1=0.f,a2=0.f,a3=0.f;
            const float4* h4 = (const float4*)hrows[s];
            DOT128(h4, wvv, a0, a1, a2, a3);
            xg1c[((size_t)b*len + ts + s)*NG + j] = bias + ((a0+a1)+(a2+a3));
        }
    }
}

// ---------------- K3: layer-1 recurrence, MFMA hi/lo, xg LDS slabs ----------------
__global__ WGA
void lstm_layer1(const float* __restrict__ xg1c,
                 const float* __restrict__ Whh1,
                 float* __restrict__ h2c,
                 float* __restrict__ hstate, float* __restrict__ cstate,
                 int t0, int len)
{
    __shared__ __align__(16) unsigned short hhi[HD], hlo[HD];
    __shared__ float gbuf[NG];
    __shared__ __align__(16) float xgs[2][SS*NG];   // 2 x 16 KB double buffer
    const int j = threadIdx.x;
    const int b = blockIdx.x;
    const int wv = j >> 6, lane = j & 63, lq = lane >> 4, lm = lane & 15;
    const bool hnd = ((j & 3) == 0);
    const int r = j >> 2;

    s8v Ah[4][4], Al[4][4];
    LOAD_A(Whh1);

    float c = 0.f, hcur = 0.f;
    if (hnd) {
        if (t0 != 0) { hcur = hstate[b*HD+r]; c = cstate[b*HD+r]; }
        unsigned short hb = bf16rne(hcur);
        hhi[r] = hb; hlo[r] = bf16rne(hcur - bf16tof(hb));
    }
    {   // prologue: stage slab 0 (8 steps x 512 gates = 4096 floats, contiguous)
        const float4* s4 = (const float4*)(xg1c + ((size_t)b*len)*NG);
        float4 p0 = s4[j], p1 = s4[j+512];
        float4* d4 = (float4*)xgs[0];
        d4[j] = p0; d4[j+512] = p1;
    }
    __syncthreads();

    for (int ts = 0; ts < len; ts += SS) {
        const int cur = (ts >> 3) & 1;
        const int ns = (len - ts < SS) ? (len - ts) : SS;
        const bool more = (ts + SS < len);
        float4 p0, p1;
        if (more) {   // issue next-slab loads NOW; ds_write after 8 steps (T14 split)
            const float4* s4 = (const float4*)(xg1c + ((size_t)b*len + ts + SS)*NG);
            p0 = s4[j]; p1 = s4[j+512];
        }
        for (int s = 0; s < ns; ++s) {
            s8v Bh[4], Bl[4];
            BUILD_B(hhi, hlo);
            MFMA_GATES();
            BAR_LGKM();                  // barrier A
            if (hnd) {
                const float* xr = xgs[cur] + (s << 9);
                float gi = gbuf[r]      + xr[r];        // K2 folded biases in
                float gf = gbuf[HD+r]   + xr[HD+r];
                float gg = gbuf[2*HD+r] + xr[2*HD+r];
                float go = gbuf[3*HD+r] + xr[3*HD+r];
                float iv = sigf(gi), fv = sigf(gf), gv = tanhfast(gg), ov = sigf(go);
                c = fmaf(fv, c, iv*gv);
                hcur = ov * tanhfast(c);
                h2c[((size_t)b*len + ts + s)*HD + r] = hcur;
                unsigned short hb = bf16rne(hcur);
                hhi[r] = hb; hlo[r] = bf16rne(hcur - bf16tof(hb));
            }
            BAR_LGKM();                  // barrier B
        }
        if (more) {
            float4* d4 = (float4*)xgs[cur ^ 1];
            d4[j] = p0; d4[j+512] = p1;  // vmcnt waited here (8 steps of slack)
            BAR_LGKM();                  // slab visible for next iteration
        }
    }
    if (hnd) { hstate[b*HD+r] = hcur; cstate[b*HD+r] = c; }
}

// ---------------- K4: y = h2 @ fcw^T + fcb — wave-per-row, fp32 ----------------
__global__ __launch_bounds__(512, 1)
void fc_head(const float* __restrict__ h2c,
             const float* __restrict__ fcw, const float* __restrict__ fcb,
             float* __restrict__ y, int t0, int len)
{
    const int b = blockIdx.x;
    const int wid = threadIdx.x >> 6;
    const int lane = threadIdx.x & 63;
    const float f0a = fcw[0*HD+lane], f0b = fcw[0*HD+64+lane];
    const float f1a = fcw[1*HD+lane], f1b = fcw[1*HD+64+lane];
    const float f2a = fcw[2*HD+lane], f2b = fcw[2*HD+64+lane];
    const float fb = (lane < 3) ? fcb[lane] : 0.f;
    for (int tc = wid; tc < len; tc += 8) {
        const float* hp = h2c + ((size_t)b*len + tc)*HD;
        float ha = hp[lane], hb = hp[64+lane];
        float y0 = ha*f0a + hb*f0b;
        float y1 = ha*f1a + hb*f1b;
        float y2 = ha*f2a + hb*f2b;
        #pragma unroll
        for (int m = 1; m < 64; m <<= 1) {
            y0 += __shfl_xor(y0, m);
            y1 += __shfl_xor(y1, m);
            y2 += __shfl_xor(y2, m);
        }
        if (lane < 3) {
            float yv = (lane==0) ? y0 : (lane==1) ? y1 : y2;
            y[((size_t)b*TT + (t0+tc))*3 + lane] = yv + fb;
        }
    }
}

extern "C" void kernel_launch(void* const* d_in, const int* in_sizes, int n_in,
                              void* d_out, int out_size, void* d_ws, size_t ws_size,
                              hipStream_t stream)
{
    const float* x    = (const float*)d_in[0];
    const float* Wih0 = (const float*)d_in[1];
    const float* Whh0 = (const float*)d_in[2];
    const float* bih0 = (const float*)d_in[3];
    const float* bhh0 = (const float*)d_in[4];
    const float* Wih1 = (const float*)d_in[5];
    const float* Whh1 = (const float*)d_in[6];
    const float* bih1 = (const float*)d_in[7];
    const float* bhh1 = (const float*)d_in[8];
    const float* fcw  = (const float*)d_in[9];
    const float* fcb  = (const float*)d_in[10];
    float* y = (float*)d_out;

    const size_t stateBytes = 4ull * NB * HD * sizeof(float);
    const size_t perT = (size_t)NB*HD*sizeof(float) + (size_t)NB*NG*sizeof(float);
    long tcl = (ws_size > stateBytes) ? (long)((ws_size - stateBytes) / perT) : 1;
    if (tcl > TT) tcl = TT;
    if (tcl < 1)  tcl = 1;
    const int Tc = (int)tcl;   // ws-derived -> deterministic

    float* h1c  = (float*)d_ws;
    float* xg1c = h1c  + (size_t)NB * Tc * HD;
    float* hs1  = xg1c + (size_t)NB * Tc * NG;
    float* cs1  = hs1 + NB*HD;
    float* hs2  = cs1 + NB*HD;
    float* cs2  = hs2 + NB*HD;
    float* h2c  = h1c;   // h1c dead after K2 — reuse for h2

    for (int t0 = 0; t0 < TT; t0 += Tc) {
        const int len = (TT - t0 < Tc) ? (TT - t0) : Tc;
        lstm_layer0<<<dim3(NB), dim3(512), 0, stream>>>(
            x, Wih0, Whh0, bih0, bhh0, h1c, hs1, cs1, t0, len);
        xgate_gemm<<<dim3(NB), dim3(512), 0, stream>>>(
            h1c, Wih1, bih1, bhh1, xg1c, len);
        lstm_layer1<<<dim3(NB), dim3(512), 0, stream>>>(
            xg1c, Whh1, h2c, hs2, cs2, t0, len);
        fc_head<<<dim3(NB), dim3(512), 0, stream>>>(
            h2c, fcw, fcb, y, t0, len);
    }
}

// Round 18
// 1938.859 us; speedup vs baseline: 2.0167x; 2.0167x over previous
//
#include <hip/hip_runtime.h>

#define NB 256      // batch
#define TT 1000     // total timesteps
#define HD 128      // hidden
#define NG 512      // 4*H, PyTorch gate order i,f,g,o

// 8 waves/block at 1 block/CU = exactly 2 waves/EU.
#define WGA __attribute__((amdgpu_flat_work_group_size(512,512), amdgpu_waves_per_eu(2,2)))

typedef __attribute__((ext_vector_type(8))) short s8v;   // 8 bf16 (MFMA A/B)
typedef __attribute__((ext_vector_type(4))) float f4v;   // MFMA C/D

__device__ __forceinline__ unsigned short bf16rne(float v) {
    unsigned u = __float_as_uint(v);
    unsigned r = u + 0x7FFF + ((u >> 16) & 1);
    return (unsigned short)(r >> 16);
}
__device__ __forceinline__ float bf16tof(unsigned short h) {
    return __uint_as_float(((unsigned)h) << 16);
}
__device__ __forceinline__ float sigf(float x) {
    return 1.f / (1.f + __expf(-x));
}
__device__ __forceinline__ float tanhfast(float x) {
    float e = __expf(-2.f * x);                 // 2*sigmoid(2x)-1, NaN-safe
    return 2.f / (1.f + e) - 1.f;
}

// r10's 128-element fp32 dot, software-pipelined with sched_barrier(0) (proven +10%).
#define DOT128(h4, wv, A0, A1, A2, A3)                                        \
    {                                                                          \
        float4 c0=(h4)[0], c1=(h4)[1], c2=(h4)[2], c3=(h4)[3];                 \
        _Pragma("unroll")                                                      \
        for (int g = 0; g < 8; ++g) {                                          \
            float4 n0,n1,n2,n3;                                                \
            if (g < 7) { n0=(h4)[4*g+4]; n1=(h4)[4*g+5];                       \
                         n2=(h4)[4*g+6]; n3=(h4)[4*g+7]; }                     \
            A0 = fmaf(c0.x, wv[4*g+0].x, A0); A1 = fmaf(c0.y, wv[4*g+0].y, A1);\
            A2 = fmaf(c0.z, wv[4*g+0].z, A2); A3 = fmaf(c0.w, wv[4*g+0].w, A3);\
            A0 = fmaf(c1.x, wv[4*g+1].x, A0); A1 = fmaf(c1.y, wv[4*g+1].y, A1);\
            A2 = fmaf(c1.z, wv[4*g+1].z, A2); A3 = fmaf(c1.w, wv[4*g+1].w, A3);\
            A0 = fmaf(c2.x, wv[4*g+2].x, A0); A1 = fmaf(c2.y, wv[4*g+2].y, A1);\
            A2 = fmaf(c2.z, wv[4*g+2].z, A2); A3 = fmaf(c2.w, wv[4*g+2].w, A3);\
            A0 = fmaf(c3.x, wv[4*g+3].x, A0); A1 = fmaf(c3.y, wv[4*g+3].y, A1);\
            A2 = fmaf(c3.z, wv[4*g+3].z, A2); A3 = fmaf(c3.w, wv[4*g+3].w, A3);\
            __builtin_amdgcn_sched_barrier(0);                                 \
            if (g < 7) { c0=n0; c1=n1; c2=n2; c3=n3; }                         \
        }                                                                      \
    }

// ---------------- K1: layer-0 recurrence (r10 exact — 371 us/chunk) ----------------
__global__ WGA
void lstm_layer0(const float* __restrict__ x,
                 const float* __restrict__ Wih, const float* __restrict__ Whh,
                 const float* __restrict__ bih, const float* __restrict__ bhh,
                 float* __restrict__ h1c,
                 float* __restrict__ hstate, float* __restrict__ cstate,
                 int t0, int len)
{
    __shared__ __align__(16) float h_lds[HD];
    __shared__ float gbuf[NG];
    __shared__ float x_lds[3 * TT];   // 12 KB
    const int j = threadIdx.x;
    const int b = blockIdx.x;

    float4 wv[HD/4];   // W_hh row j
    {
        const float4* wr = (const float4*)(Whh + (size_t)j * HD);
        #pragma unroll
        for (int q = 0; q < HD/4; ++q) wv[q] = wr[q];
    }
    const float wx0 = Wih[j*3+0], wx1 = Wih[j*3+1], wx2 = Wih[j*3+2];
    const float bias = bih[j] + bhh[j];

    for (int idx = j; idx < 3*len; idx += 512)
        x_lds[idx] = x[((size_t)b*TT + t0)*3 + idx];

    float c = 0.f, hcur = 0.f;
    if (j < HD) {
        if (t0 != 0) { hcur = hstate[b*HD+j]; c = cstate[b*HD+j]; }
        h_lds[j] = hcur;
    }
    __syncthreads();

    const int gtype = j >> 7;   // 0:i 1:f 2:g 3:o — wave-uniform
    for (int tc = 0; tc < len; ++tc) {
        float a0=0.f,a1=0.f,a2=0.f,a3=0.f;
        const float4* h4 = (const float4*)h_lds;   // uniform addr -> LDS broadcast
        DOT128(h4, wv, a0, a1, a2, a3);
        float acc = bias + ((a0+a1)+(a2+a3));
        acc = fmaf(wx0, x_lds[3*tc+0], acc);
        acc = fmaf(wx1, x_lds[3*tc+1], acc);
        acc = fmaf(wx2, x_lds[3*tc+2], acc);
        float act = (gtype == 2) ? tanhfast(acc) : sigf(acc);
        gbuf[j] = act;
        __syncthreads();                 // barrier A: gates visible
        if (j < HD) {
            float ig = gbuf[j], fg = gbuf[HD+j], gg = gbuf[2*HD+j], og = gbuf[3*HD+j];
            c = fmaf(fg, c, ig*gg);
            hcur = og * tanhfast(c);
            h_lds[j] = hcur;
            h1c[((size_t)b*len + tc)*HD + j] = hcur;
        }
        __syncthreads();                 // barrier B: new h visible
    }
    if (j < HD) { hstate[b*HD+j] = hcur; cstate[b*HD+j] = c; }
}

// ---------------- K2: xg1 = h1 @ W_ih_l1^T + biases — MFMA GEMM over timestep tiles ----------------
// No recurrence -> N dimension = 16 timesteps per tile, no in-loop barriers.
// A = W_ih_l1 rows (hi/lo bf16, r12-verified map); B cols = 16 h1 timesteps.
// 3-pass hi/lo: D = Ah*Bh + (Al*Bh + Ah*Bl), fp32 accumulate.
__global__ WGA
void xgate_gemm(const float* __restrict__ h1c,
                const float* __restrict__ Wih1,
                const float* __restrict__ bih1, const float* __restrict__ bhh1,
                float* __restrict__ xg1c, int len)
{
    __shared__ float bsum[NG];
    const int j = threadIdx.x;
    const int b = blockIdx.x;
    const int wv = j >> 6, lane = j & 63, lq = lane >> 4, lm = lane & 15;

    // A-fragments: W rows [64*wv, 64*wv+64), hi/lo split (r12-verified layout):
    // m = lm, k = 32*kc + 4*lq + (e&3) + 16*(e>>2)
    s8v Ah[4][4], Al[4][4];
    {
        #pragma unroll
        for (int t = 0; t < 4; ++t) {
            const int m = 64*wv + 16*t + lm;
            const float* wrow = Wih1 + (size_t)m * HD;
            #pragma unroll
            for (int kc = 0; kc < 4; ++kc) {
                const int k0 = 32*kc + 4*lq;
                float4 va = *(const float4*)(wrow + k0);
                float4 vb = *(const float4*)(wrow + k0 + 16);
                float vs[8] = {va.x,va.y,va.z,va.w,vb.x,vb.y,vb.z,vb.w};
                s8v ah, al;
                #pragma unroll
                for (int e = 0; e < 8; ++e) {
                    unsigned short hb = bf16rne(vs[e]);
                    float lo = vs[e] - bf16tof(hb);
                    ah[e] = (short)hb; al[e] = (short)bf16rne(lo);
                }
                Ah[t][kc] = ah; Al[t][kc] = al;
            }
        }
    }
    bsum[j] = bih1[j] + bhh1[j];
    __syncthreads();

    for (int ts = 0; ts < len; ts += 16) {
        // B-fragments: n = lm (timestep ts+lm), k = 32*kc + 4*lq + (e&3) + 16*(e>>2)
        const int trow = (ts + lm < len) ? (ts + lm) : (len - 1);
        const float* hrow = h1c + ((size_t)b*len + trow)*HD;
        s8v Bh[4], Bl[4];
        #pragma unroll
        for (int kc = 0; kc < 4; ++kc) {
            const int k0 = 32*kc + 4*lq;
            float4 va = *(const float4*)(hrow + k0);
            float4 vb = *(const float4*)(hrow + k0 + 16);
            float vs[8] = {va.x,va.y,va.z,va.w,vb.x,vb.y,vb.z,vb.w};
            s8v hh, hl;
            #pragma unroll
            for (int e = 0; e < 8; ++e) {
                unsigned short hb = bf16rne(vs[e]);
                float lo = vs[e] - bf16tof(hb);
                hh[e] = (short)hb; hl[e] = (short)bf16rne(lo);
            }
            Bh[kc] = hh; Bl[kc] = hl;
        }
        f4v zz = {0.f,0.f,0.f,0.f};
        f4v accA[4] = {zz,zz,zz,zz}, accB[4] = {zz,zz,zz,zz};
        #pragma unroll
        for (int kc = 0; kc < 4; ++kc) {
            #pragma unroll
            for (int t = 0; t < 4; ++t)
                accA[t] = __builtin_amdgcn_mfma_f32_16x16x32_bf16(Ah[t][kc], Bh[kc], accA[t], 0,0,0);
        }
        #pragma unroll
        for (int kc = 0; kc < 4; ++kc) {
            #pragma unroll
            for (int t = 0; t < 4; ++t)
                accB[t] = __builtin_amdgcn_mfma_f32_16x16x32_bf16(Al[t][kc], Bh[kc], accB[t], 0,0,0);
        }
        #pragma unroll
        for (int kc = 0; kc < 4; ++kc) {
            #pragma unroll
            for (int t = 0; t < 4; ++t)
                accB[t] = __builtin_amdgcn_mfma_f32_16x16x32_bf16(Ah[t][kc], Bl[kc], accB[t], 0,0,0);
        }
        // D write (r12-verified C/D map): lane holds col=lm (timestep), rows 4*lq+reg.
        if (ts + lm < len) {
            float* xrow = xg1c + ((size_t)b*len + ts + lm)*NG;
            #pragma unroll
            for (int t = 0; t < 4; ++t) {
                const int r0 = 64*wv + 16*t + 4*lq;
                float4 o;
                o.x = accA[t][0]+accB[t][0] + bsum[r0+0];
                o.y = accA[t][1]+accB[t][1] + bsum[r0+1];
                o.z = accA[t][2]+accB[t][2] + bsum[r0+2];
                o.w = accA[t][3]+accB[t][3] + bsum[r0+3];
                *(float4*)&xrow[r0] = o;
            }
        }
    }
}

// ---------------- K3: layer-1 recurrence (r10 exact — ~357 us/chunk) ----------------
__global__ WGA
void lstm_layer1(const float* __restrict__ xg1c,
                 const float* __restrict__ Whh1,
                 float* __restrict__ h2c,
                 float* __restrict__ hstate, float* __restrict__ cstate,
                 int t0, int len)
{
    __shared__ __align__(16) float h_lds[HD];
    __shared__ float gbuf[NG];
    const int j = threadIdx.x;
    const int b = blockIdx.x;
    float4 wv[HD/4];   // W_hh_l1 row j
    {
        const float4* wr = (const float4*)(Whh1 + (size_t)j * HD);
        #pragma unroll
        for (int q = 0; q < HD/4; ++q) wv[q] = wr[q];
    }
    float c = 0.f, hcur = 0.f;
    if (j < HD) {
        if (t0 != 0) { hcur = hstate[b*HD+j]; c = cstate[b*HD+j]; }
        h_lds[j] = hcur;
    }
    __syncthreads();
    const int gtype = j >> 7;
    float xg_cur = xg1c[((size_t)b*len + 0)*NG + j];
    for (int tc = 0; tc < len; ++tc) {
        float xg_nxt = 0.f;
        if (tc+1 < len) xg_nxt = xg1c[((size_t)b*len + tc+1)*NG + j]; // prefetch
        float a0=0.f,a1=0.f,a2=0.f,a3=0.f;
        const float4* h4 = (const float4*)h_lds;
        DOT128(h4, wv, a0, a1, a2, a3);
        float acc = xg_cur + ((a0+a1)+(a2+a3));
        float act = (gtype == 2) ? tanhfast(acc) : sigf(acc);
        gbuf[j] = act;
        __syncthreads();                 // barrier A
        if (j < HD) {
            float ig = gbuf[j], fg = gbuf[HD+j], gg = gbuf[2*HD+j], og = gbuf[3*HD+j];
            c = fmaf(fg, c, ig*gg);
            hcur = og * tanhfast(c);
            h_lds[j] = hcur;
            h2c[((size_t)b*len + tc)*HD + j] = hcur;
        }
        __syncthreads();                 // barrier B
        xg_cur = xg_nxt;
    }
    if (j < HD) { hstate[b*HD+j] = hcur; cstate[b*HD+j] = c; }
}

// ---------------- K4: y = h2 @ fcw^T + fcb — wave-per-row, fp32, deterministic ----------------
__global__ __launch_bounds__(512, 1)
void fc_head(const float* __restrict__ h2c,
             const float* __restrict__ fcw, const float* __restrict__ fcb,
             float* __restrict__ y, int t0, int len)
{
    const int b = blockIdx.x;
    const int wid = threadIdx.x >> 6;   // 0..7
    const int lane = threadIdx.x & 63;
    const float f0a = fcw[0*HD+lane], f0b = fcw[0*HD+64+lane];
    const float f1a = fcw[1*HD+lane], f1b = fcw[1*HD+64+lane];
    const float f2a = fcw[2*HD+lane], f2b = fcw[2*HD+64+lane];
    const float fb = (lane < 3) ? fcb[lane] : 0.f;
    for (int tc = wid; tc < len; tc += 8) {
        const float* hp = h2c + ((size_t)b*len + tc)*HD;
        float ha = hp[lane], hb = hp[64+lane];
        float y0 = ha*f0a + hb*f0b;
        float y1 = ha*f1a + hb*f1b;
        float y2 = ha*f2a + hb*f2b;
        #pragma unroll
        for (int m = 1; m < 64; m <<= 1) {
            y0 += __shfl_xor(y0, m);
            y1 += __shfl_xor(y1, m);
            y2 += __shfl_xor(y2, m);
        }
        if (lane < 3) {
            float yv = (lane==0) ? y0 : (lane==1) ? y1 : y2;
            y[((size_t)b*TT + (t0+tc))*3 + lane] = yv + fb;
        }
    }
}

extern "C" void kernel_launch(void* const* d_in, const int* in_sizes, int n_in,
                              void* d_out, int out_size, void* d_ws, size_t ws_size,
                              hipStream_t stream)
{
    const float* x    = (const float*)d_in[0];
    const float* Wih0 = (const float*)d_in[1];
    const float* Whh0 = (const float*)d_in[2];
    const float* bih0 = (const float*)d_in[3];
    const float* bhh0 = (const float*)d_in[4];
    const float* Wih1 = (const float*)d_in[5];
    const float* Whh1 = (const float*)d_in[6];
    const float* bih1 = (const float*)d_in[7];
    const float* bhh1 = (const float*)d_in[8];
    const float* fcw  = (const float*)d_in[9];
    const float* fcb  = (const float*)d_in[10];
    float* y = (float*)d_out;

    // ws layout: h1 chunk + xg1 chunk + 4 state bufs (ws-derived -> deterministic)
    const size_t stateBytes = 4ull * NB * HD * sizeof(float);
    const size_t perT = (size_t)NB*HD*sizeof(float) + (size_t)NB*NG*sizeof(float);
    long tcl = (ws_size > stateBytes) ? (long)((ws_size - stateBytes) / perT) : 1;
    if (tcl > TT) tcl = TT;
    if (tcl < 1)  tcl = 1;
    const int Tc = (int)tcl;

    float* h1c  = (float*)d_ws;
    float* xg1c = h1c  + (size_t)NB * Tc * HD;
    float* hs1  = xg1c + (size_t)NB * Tc * NG;
    float* cs1  = hs1 + NB*HD;
    float* hs2  = cs1 + NB*HD;
    float* cs2  = hs2 + NB*HD;
    float* h2c  = h1c;   // h1c dead after K2 — reuse for h2

    for (int t0 = 0; t0 < TT; t0 += Tc) {
        const int len = (TT - t0 < Tc) ? (TT - t0) : Tc;
        lstm_layer0<<<dim3(NB), dim3(512), 0, stream>>>(
            x, Wih0, Whh0, bih0, bhh0, h1c, hs1, cs1, t0, len);
        xgate_gemm<<<dim3(NB), dim3(512), 0, stream>>>(
            h1c, Wih1, bih1, bhh1, xg1c, len);
        lstm_layer1<<<dim3(NB), dim3(512), 0, stream>>>(
            xg1c, Whh1, h2c, hs2, cs2, t0, len);
        fc_head<<<dim3(NB), dim3(512), 0, stream>>>(
            h2c, fcw, fcb, y, t0, len);
    }
}